// Round 3
// baseline (284.235 us; speedup 1.0000x reference)
//
#include <hip/hip_runtime.h>
#include <hip/hip_bf16.h>

// FeatureSimilarity l2: out[i][j] = -sqrt(max(sq[i] + sq[j] - 2*<f_i, f_j>, 0))
// N=8192, D=128, fp32 in/out.
//
// Session model (R3 dispatch accounting): timed region = ~170 us fixed 1-GiB
// ws re-poison fill + ~6 us convert + ~95-100 us gemm. Only the gemm is
// controllable; its floor is ~50-60 us (268 MB stores = 43 us @ 6.3 TB/s).
//
// R1 (279.1): swizzled bf16 fragment layout fbT, coalesced frag loads,
//             transposed coalesced epilogue stores.
// R2 (288.9): nt stores — refuted, reverted.
// R3 (274.6): 128x64 tile, occupancy bump — +4.5 us only.
// R4 (this round): SYMMETRY. Launch only upper-triangular 128x128 tiles
//   (2080 of 4096). Each block computes its tile once and writes it twice:
//   (a) direct transposed write out[col][row]  -> lower-mirror block (tj,ti)
//   (b) LDS-transposed write    out[row][col]  -> upper block (ti,tj),
//       per-wave 64x32 strips, XOR-swizzled (write b32 conflict-free at
//       floor, read b128 at floor), 128 B contiguous store segments.
//   Halves MFMA + fragment L2 reads + sqrt epilogue VALU; store bytes
//   unchanged (the true floor). Mirror values bitwise-identical to direct.

typedef __attribute__((ext_vector_type(8))) short short8;    // 8 bf16 = 4 VGPRs
typedef __attribute__((ext_vector_type(4))) float float4v;   // MFMA acc

#define FS_N 8192
#define FS_D 128

// RNE fp32 -> bf16 (matches MFMA input rounding)
static __device__ __forceinline__ unsigned short f32_to_bf16_rne(float x) {
    unsigned u = __float_as_uint(x);
    u += 0x7FFFu + ((u >> 16) & 1u);
    return (unsigned short)(u >> 16);
}
static __device__ __forceinline__ float bf16_to_f32(unsigned short b) {
    return __uint_as_float(((unsigned)b) << 16);
}

// Kernel 1: fp32 F -> bf16 in MFMA-fragment-swizzled layout
//   fbT[((rt*4 + ks)*64 + quad*16 + l15)*8 + e]  holds  F_bf16[rt*16+l15][ks*32+quad*8+e]
// and sq[row] = sum(bf16(f_row)^2) in fp32.
__global__ __launch_bounds__(256) void fs_convert_kernel(
        const float* __restrict__ in, unsigned short* __restrict__ fbT,
        float* __restrict__ sq) {
    const int rt = blockIdx.x;           // 0..511
    const int t  = threadIdx.x;
    const int rl = t >> 4;               // row within tile, 0..15
    const int g  = t & 15;               // 8-element k-group, 0..15
    const int row = rt * 16 + rl;

    const float4* src = (const float4*)(in + row * FS_D + g * 8);
    const float4 v0 = src[0];
    const float4 v1 = src[1];

    short8 packed;
    float s = 0.0f;
    {
        const float vv[8] = {v0.x, v0.y, v0.z, v0.w, v1.x, v1.y, v1.z, v1.w};
        #pragma unroll
        for (int e = 0; e < 8; ++e) {
            const unsigned short b = f32_to_bf16_rne(vv[e]);
            packed[e] = (short)b;
            const float f = bf16_to_f32(b);
            s += f * f;
        }
    }

    // swizzled store: ks = g>>2, quad = g&3, lane_in_frag = quad*16 + rl
    const int ks   = g >> 2;
    const int quad = g & 3;
    short8* dst = (short8*)(fbT + (((size_t)(rt * 4 + ks) * 64) + quad * 16 + rl) * 8);
    *dst = packed;

    #pragma unroll
    for (int off = 8; off > 0; off >>= 1) s += __shfl_xor(s, off);
    if (g == 0) sq[row] = s;
}

// Kernel 2: one 128x128 tile per block, upper triangle only (ti <= tj).
// 4 waves in 2x2, each 64x64 via acc[4][4] of 16x16x32 bf16 MFMA, K=128.
__global__ __launch_bounds__(256) void fs_gemm_kernel(
        const unsigned short* __restrict__ fbT, const float* __restrict__ sq,
        float* __restrict__ out) {
    const int ti = blockIdx.x;            // 0..63 (rows tile)
    const int tj = blockIdx.y;            // 0..63 (cols tile)
    if (tj < ti) return;                  // upper triangle only (uniform)

    __shared__ float T[4][2048];          // per-wave 64x32 f32 strip, XOR-swizzled (32 KB)

    const int wid  = threadIdx.x >> 6;
    const int lane = threadIdx.x & 63;
    const int wm   = wid >> 1, wn = wid & 1;
    const int l15  = lane & 15;
    const int quad = lane >> 4;

    const int arow = ti * 128 + wm * 64;  // A rows this wave covers (+0..63)
    const int brow = tj * 128 + wn * 64;  // B rows (= output cols)

    const int rta = ti * 8 + wm * 4;
    const int rtb = tj * 8 + wn * 4;

    float4v acc[4][4];
    #pragma unroll
    for (int m = 0; m < 4; ++m)
        #pragma unroll
        for (int n = 0; n < 4; ++n)
            acc[m][n] = (float4v){0.f, 0.f, 0.f, 0.f};

    #pragma unroll
    for (int ks = 0; ks < 4; ++ks) {
        short8 a[4], b[4];
        #pragma unroll
        for (int m = 0; m < 4; ++m)
            a[m] = *(const short8*)(fbT + (size_t)((rta + m) * 4 + ks) * 512 + lane * 8);
        #pragma unroll
        for (int n = 0; n < 4; ++n)
            b[n] = *(const short8*)(fbT + (size_t)((rtb + n) * 4 + ks) * 512 + lane * 8);
        #pragma unroll
        for (int m = 0; m < 4; ++m)
            #pragma unroll
            for (int n = 0; n < 4; ++n)
                acc[m][n] = __builtin_amdgcn_mfma_f32_16x16x32_bf16(
                    a[m], b[n], acc[m][n], 0, 0, 0);
    }

    // Pass 1: direct transposed write out[col][row] — covers block (tj,ti)
    // (for ti==tj this is the complete diagonal tile). C/D layout (16x16):
    // col = l15, row = quad*4 + r. Each lane stores contiguous float4 over r.
    // The g-applied values are kept in acc[][] for the mirror pass.
    #pragma unroll
    for (int n = 0; n < 4; ++n) {
        const int   col = brow + n * 16 + l15;
        const float sqc = sq[col];
        float* outcol = out + (size_t)col * FS_N;
        #pragma unroll
        for (int m = 0; m < 4; ++m) {
            const int rbase = arow + m * 16 + quad * 4;
            const float4v sqr = *(const float4v*)(sq + rbase);
            float4v o;
            #pragma unroll
            for (int r = 0; r < 4; ++r) {
                float d2 = sqr[r] + sqc - 2.0f * acc[m][n][r];
                d2 = fmaxf(d2, 0.0f);
                o[r] = -__builtin_sqrtf(d2);
            }
            *(float4v*)(outcol + rbase) = o;
            acc[m][n] = o;                 // reuse acc regs as the o-tile
        }
    }

    if (ti == tj) return;                  // diagonal: single write (uniform)

    // Pass 2: mirror write out[row][col] — covers block (ti,tj).
    // Per-wave private LDS transpose in two 64x32 strips.
    //   logical (x,y'') -> physical word x*32 + (y'' ^ ((x&7)<<2))
    // Writes: b32, 32 distinct banks (2 lanes/bank = floor, free).
    // Reads:  b128, 8 words/bank = b128 floor (conflict-free).
    float* Tw = T[wid];
    #pragma unroll
    for (int sp = 0; sp < 2; ++sp) {
        __syncthreads();                   // (sp=1) prior reads drained before overwrite
        #pragma unroll
        for (int nn = 0; nn < 2; ++nn) {
            const int n = sp * 2 + nn;
            #pragma unroll
            for (int m = 0; m < 4; ++m) {
                #pragma unroll
                for (int r = 0; r < 4; ++r) {
                    const int x  = m * 16 + quad * 4 + r;
                    const int yy = nn * 16 + l15;
                    Tw[x * 32 + (yy ^ ((x & 7) << 2))] = acc[m][n][r];
                }
            }
        }
        __syncthreads();                   // writes drained (lgkmcnt(0) + barrier)
        #pragma unroll
        for (int s = 0; s < 8; ++s) {
            const int xp   = s * 8 + quad * 2 + (l15 >> 3);
            const int fidx = xp * 8 + ((l15 & 7) ^ (xp & 7));
            const float4v o2 = ((const float4v*)Tw)[fidx];
            *(float4v*)(out + (size_t)(arow + xp) * FS_N
                            + brow + sp * 32 + (l15 & 7) * 4) = o2;
        }
    }
}

extern "C" void kernel_launch(void* const* d_in, const int* in_sizes, int n_in,
                              void* d_out, int out_size, void* d_ws, size_t ws_size,
                              hipStream_t stream) {
    const float* features = (const float*)d_in[0];
    float*       out      = (float*)d_out;

    // ws layout: [0, 2MB) swizzled bf16 features; then fp32 row sum-of-squares
    unsigned short* fbT = (unsigned short*)d_ws;
    float*          sq  = (float*)((char*)d_ws + (size_t)FS_N * FS_D * sizeof(unsigned short));

    fs_convert_kernel<<<FS_N / 16, 256, 0, stream>>>(features, fbT, sq);

    dim3 grid(FS_N / 128, FS_N / 128);     // tj < ti blocks early-exit
    fs_gemm_kernel<<<grid, 256, 0, stream>>>(fbT, sq, out);
}